// Round 13
// baseline (204.133 us; speedup 1.0000x reference)
//
#include <hip/hip_runtime.h>
#include <hip/hip_bf16.h>

// Problem constants (reference: N, E, K, F_IN, H = 50000, 640000, 3, 128, 128)
#define NN 50000
#define NE 640000
#define NP 196          // ceil(NN/256) zero blocks
#define CAP 64          // bucket capacity; deg~Poisson(12.8), P(deg>=64)~5e-27
#define NGB 782         // gates blocks: ceil(NN/64); blocks 0..624 also fill (NE/1024=625)

typedef unsigned short ushort_t;
typedef unsigned int uint_t;
typedef __attribute__((ext_vector_type(8))) short bf16x8;   // 8 bf16 = 4 VGPRs
typedef __attribute__((ext_vector_type(4))) float f32x4;

__device__ __forceinline__ float b2f(ushort_t u) {
    union { uint_t u; float f; } v; v.u = ((uint_t)u) << 16; return v.f;
}
__device__ __forceinline__ ushort_t f2b(float f) {
    union { float f; uint_t u; } v; v.f = f;
    uint_t u = v.u;
    uint_t r = u + 0x7fffu + ((u >> 16) & 1u);   // round-nearest-even
    return (ushort_t)(r >> 16);
}
// fast transcendentals: v_exp + v_rcp (err ~1e-6, vs 4.9e-4 pipeline absmax)
__device__ __forceinline__ float fsig(float x)  { return __builtin_amdgcn_rcpf(1.0f + __expf(-x)); }
__device__ __forceinline__ float ftanh(float x) { return 1.0f - 2.0f * __builtin_amdgcn_rcpf(1.0f + __expf(2.0f * x)); }
// mode-aware scalar param load: mf=1 -> f32 array, mf=0 -> bf16 array
__device__ __forceinline__ float ldm(const void* p, int i, int mf) {
    return mf ? ((const float*)p)[i] : b2f(((const ushort_t*)p)[i]);
}

// ---- workspace layout (bytes), total 25.93 MB (known-good ceiling: 31.65 MB) ----
#define OFF_HB   0            // NN*128 bf16 (12,800,000)  raw h (post-gcn_w), bf16
#define OFF_BSRC 12800000     // NN*CAP i32 (12,800,000)   fixed-capacity dst buckets
#define OFF_CNT  25600000     // NN i32     (200,000)      in-degree (bucket fill count)
#define OFF_WT   25800000     // 4*16384 bf16 (131,072)    Wi^T, Wc^T, Wo^T, gcn_w^T ([f][k])
#define OFF_COEF 25931072     // 641 f32    (2,564)
#define OFF_MODE 25933640     // i32
#define WS_REQ   25933648

__global__ void fb_k(ushort_t* __restrict__ out, int n) {   // ws too small: diagnostic zeros
    int i = blockIdx.x * blockDim.x + threadIdx.x;
    if (i < n) out[i] = 0;
}

// blocks 0..NP-1: zero cnt. block NP: dtype detect (f32-as-bf16 halves show
// huge exponents ~25% >= 0xC0; real bf16 N(0,1) never does).
__global__ void init_k(const ushort_t* __restrict__ x, int* __restrict__ cnt,
                       int* __restrict__ mode) {
    __shared__ int s[256];
    int b = blockIdx.x, t = threadIdx.x;
    if (b < NP) {
        int i = b * 256 + t;
        if (i < NN) cnt[i] = 0;
    } else {
        int bad = 0;
        for (int i = t; i < 4096; i += 256) {
            int e = (x[i] >> 7) & 0xFF;
            if (e >= 0xC0) bad++;
        }
        s[t] = bad; __syncthreads();
        for (int o = 128; o >= 1; o >>= 1) { if (t < o) s[t] += s[t + o]; __syncthreads(); }
        if (t == 0) mode[0] = (s[0] > 8) ? 1 : 0;   // 1 = f32 inputs, 0 = bf16
    }
}

// blocks 0..31: transpose W_x[0],W_x[2],W_x[3],gcn_w -> bf16 [f][k] with
// coalesced 16B reads + fire-and-forget scattered stores.
// block 32: fold biases (cheb(0)=theta_b), peephole w_c[2], relu->BN->linear tail.
__global__ void prep_k(const void* __restrict__ Wx, const void* __restrict__ gcnw,
                       const void* __restrict__ wc, const void* __restrict__ bb,
                       const void* __restrict__ thb,
                       const void* __restrict__ gam, const void* __restrict__ bet,
                       const void* __restrict__ mea, const void* __restrict__ var,
                       const void* __restrict__ linw, const void* __restrict__ linb,
                       const int* __restrict__ mode,
                       ushort_t* __restrict__ WT, float* __restrict__ coef) {
    __shared__ float red[128];
    int b = blockIdx.x, t = threadIdx.x;
    int mf = mode[0];
    if (b < 32) {
        int gid = b * 256 + t;          // 0..8191, 2048 threads/matrix
        int m  = gid >> 11;
        int u  = gid & 2047;
        int k  = u >> 4;
        int f0 = (u & 15) << 3;
        const int srcoff[4] = { 0, 2 * 16384, 3 * 16384, 0 };
        const void* S = (m == 3) ? gcnw : Wx;
        int sbase = srcoff[m] + k * 128 + f0;
        ushort_t vals[8];
        if (mf == 0) {
            bf16x8 v = *(const bf16x8*)((const ushort_t*)S + sbase);
            #pragma unroll
            for (int i = 0; i < 8; i++) vals[i] = (ushort_t)v[i];
        } else {
            const float* Sf = (const float*)S + sbase;
            #pragma unroll
            for (int i = 0; i < 8; i++) vals[i] = f2b(Sf[i]);
        }
        ushort_t* D = WT + m * 16384 + k;
        #pragma unroll
        for (int i = 0; i < 8; i++) D[(f0 + i) * 128] = vals[i];
    } else {
        if (t < 128) {
            float rs = rsqrtf(ldm(var, t, mf) + 1e-5f);
            float ga = ldm(gam, t, mf);
            float lw = ldm(linw, t, mf);
            coef[t]       = ldm(thb, t, mf)           + ldm(bb, t, mf);            // bias_i
            coef[128 + t] = ldm(thb, 2 * 128 + t, mf) + ldm(bb, 2 * 128 + t, mf);  // bias_c
            coef[256 + t] = ldm(thb, 3 * 128 + t, mf) + ldm(bb, 3 * 128 + t, mf);  // bias_o
            coef[384 + t] = ldm(wc, 2 * 128 + t, mf);                              // w_c[2]
            coef[512 + t] = ga * rs * lw;                                          // s[f]
            red[t] = (ldm(bet, t, mf) - ldm(mea, t, mf) * ga * rs) * lw;
        }
        __syncthreads();
        for (int off = 64; off >= 1; off >>= 1) {
            if (t < off && t < 128) red[t] += red[t + off];
            __syncthreads();
        }
        if (t == 0) coef[640] = red[0] + ldm(linb, 0, mf);                         // C
    }
}

// ---------------------------------------------------------------------------
// R13 homogeneous fused kernel: EVERY block does gates GEMM; blocks 0..624
// also bucket a 1024-edge quota (4/thread int4). Atomics issue after the
// A-frag barrier; returns consumed (bucket stores) only after the post-Hs
// barrier -> the ~300-600cy contended-atomic latency hides under stage-1
// MFMA/transcendentals. (R12's 5:4 heterogeneous interleave left a gates-only
// tail: gafi 60us vs fill-wall 45 + gates 25.)
//   gates: one block = 4 waves = 64 nodes; wave w owns feature cols
//   [32w,32w+32) (B-frags load once, reuse over 4 row tiles). Stores RAW h
//   (no dg pre-scale) so gates never reads cnt while fill updates it.
//   MFMA f32_16x16x32_bf16 layouts (HW-verified):
//   A: a[j]=A[m=lane&15][k=(lane>>4)*8+j];  B: b[j]=B[k=(lane>>4)*8+j][n=lane&15]
//   D: reg r -> row (lane>>4)*4+r, col lane&15
// ---------------------------------------------------------------------------
__launch_bounds__(256)
__global__ void gafi_k(const void* __restrict__ x, const ushort_t* __restrict__ WT,
                       const float* __restrict__ coef, const int* __restrict__ mode,
                       ushort_t* __restrict__ hb,
                       const int* __restrict__ ei, int* __restrict__ cnt,
                       int* __restrict__ bsrc) {
    __shared__ ushort_t tile[64 * 136];   // +8 pad: row stride 272B
    int b = blockIdx.x, t = threadIdx.x;
    bool doFill = (b < 625);              // 625*256*4 = NE exactly
    int4 s4, d4;
    if (doFill) {
        int tid = b * 256 + t;
        s4 = ((const int4*)ei)[tid];
        d4 = ((const int4*)(ei + NE))[tid];
    }

    int base = b * 64;
    int mf = mode[0];
    for (int i = 0; i < 4; i++) {
        int idx = (i * 256 + t) * 8;
        int row = idx >> 7, col = idx & 127;
        int n = base + row;
        bf16x8 v;
        if (n >= NN) {
            v = (bf16x8)0;
        } else if (mf == 0) {
            v = *(const bf16x8*)((const ushort_t*)x + n * 128 + col);
        } else {
            const float* xf = (const float*)x + n * 128 + col;
            float4 lo = *(const float4*)xf;
            float4 hi = *(const float4*)(xf + 4);
            v[0] = (short)f2b(lo.x); v[1] = (short)f2b(lo.y);
            v[2] = (short)f2b(lo.z); v[3] = (short)f2b(lo.w);
            v[4] = (short)f2b(hi.x); v[5] = (short)f2b(hi.y);
            v[6] = (short)f2b(hi.z); v[7] = (short)f2b(hi.w);
        }
        *(bf16x8*)&tile[row * 136 + col] = v;
    }
    __syncthreads();

    int lane = t & 63, wave = t >> 6;
    int m = lane & 15, quad = lane >> 4;

    bf16x8 a[4][4];
    #pragma unroll
    for (int rt = 0; rt < 4; rt++)
        #pragma unroll
        for (int kt = 0; kt < 4; kt++)
            a[rt][kt] = *(const bf16x8*)&tile[(rt * 16 + m) * 136 + kt * 32 + quad * 8];
    __syncthreads();   // all x reads done before Hs overwrites tile

    // issue returning atomics NOW: stage-1 below (12 MFMA chains + 128 lanes of
    // exp/rcp) covers their latency; returns consumed after the next barrier.
    int p0, p1, p2, p3;
    if (doFill) {
        p0 = atomicAdd(&cnt[d4.x], 1);
        p1 = atomicAdd(&cnt[d4.y], 1);
        p2 = atomicAdd(&cnt[d4.z], 1);
        p3 = atomicAdd(&cnt[d4.w], 1);
    }

    const ushort_t* WTi = WT;
    const ushort_t* WTc = WT + 16384;
    const ushort_t* WTo = WT + 2 * 16384;

    #pragma unroll
    for (int ft = 0; ft < 2; ft++) {
        int f = wave * 32 + ft * 16 + m;
        bf16x8 bi[4], bc[4], bo[4];
        #pragma unroll
        for (int kt = 0; kt < 4; kt++) {
            int off = f * 128 + kt * 32 + quad * 8;
            bi[kt] = *(const bf16x8*)(WTi + off);
            bc[kt] = *(const bf16x8*)(WTc + off);
            bo[kt] = *(const bf16x8*)(WTo + off);
        }
        float bi_f = coef[f], bc_f = coef[128 + f], bo_f = coef[256 + f], w2 = coef[384 + f];
        #pragma unroll
        for (int rt = 0; rt < 4; rt++) {
            f32x4 ai = {0,0,0,0}, ac = {0,0,0,0}, ao = {0,0,0,0};
            #pragma unroll
            for (int kt = 0; kt < 4; kt++) {
                ai = __builtin_amdgcn_mfma_f32_16x16x32_bf16(a[rt][kt], bi[kt], ai, 0, 0, 0);
                ac = __builtin_amdgcn_mfma_f32_16x16x32_bf16(a[rt][kt], bc[kt], ac, 0, 0, 0);
                ao = __builtin_amdgcn_mfma_f32_16x16x32_bf16(a[rt][kt], bo[kt], ao, 0, 0, 0);
            }
            #pragma unroll
            for (int r = 0; r < 4; r++) {
                float I  = fsig(ai[r] + bi_f);
                float T  = ftanh(ac[r] + bc_f);
                float Cs = I * T;                       // F*C_prev = 0
                float O  = fsig(ao[r] + w2 * Cs + bo_f);
                float Hs = O * ftanh(Cs);
                tile[(rt * 16 + quad * 4 + r) * 136 + f] = f2b(Hs);
            }
        }
    }
    __syncthreads();   // Hs tile complete; also drains the atomics (hidden)

    if (doFill) {      // consume atomic returns: fire-and-forget bucket stores
        if (p0 < CAP) bsrc[d4.x * CAP + p0] = s4.x;
        if (p1 < CAP) bsrc[d4.y * CAP + p1] = s4.y;
        if (p2 < CAP) bsrc[d4.z * CAP + p2] = s4.z;
        if (p3 < CAP) bsrc[d4.w * CAP + p3] = s4.w;
    }

    const ushort_t* WTg = WT + 3 * 16384;
    bf16x8 ah[4][4];
    #pragma unroll
    for (int rt = 0; rt < 4; rt++)
        #pragma unroll
        for (int kt = 0; kt < 4; kt++)
            ah[rt][kt] = *(const bf16x8*)&tile[(rt * 16 + m) * 136 + kt * 32 + quad * 8];

    #pragma unroll
    for (int ft = 0; ft < 2; ft++) {
        int f = wave * 32 + ft * 16 + m;
        bf16x8 bg[4];
        #pragma unroll
        for (int kt = 0; kt < 4; kt++)
            bg[kt] = *(const bf16x8*)(WTg + f * 128 + kt * 32 + quad * 8);
        #pragma unroll
        for (int rt = 0; rt < 4; rt++) {
            f32x4 acc = {0,0,0,0};
            #pragma unroll
            for (int kt = 0; kt < 4; kt++)
                acc = __builtin_amdgcn_mfma_f32_16x16x32_bf16(ah[rt][kt], bg[kt], acc, 0, 0, 0);
            #pragma unroll
            for (int r = 0; r < 4; r++) {
                int n = base + rt * 16 + quad * 4 + r;
                if (n < NN) hb[n * 128 + f] = f2b(acc[r]);   // RAW h (no dg pre-scale)
            }
        }
    }
}

// ---------------------------------------------------------------------------
// Fused gather + self-loop + relu->BN->linear. One wave per destination.
// Half-wave per edge; R13: 4-deep ILP — uniform outer loop (jj += 8), each
// half issues 4 in-bounds slot loads unconditionally and 4 predicated
// cnt+row loads (8 row-loads in flight per wave; R12 had 4). No cross-lane
// ops in the loop (R8's divergent-shfl trap stays dead).
// g[d] = dg[d]*(sum_e dg[s]*h[s] + dg[d]*h[d]);  dg from L2-resident cnt.
// ---------------------------------------------------------------------------
__launch_bounds__(256)
__global__ void gat_out_k(const ushort_t* __restrict__ hb, const int* __restrict__ cnt,
                          const int* __restrict__ bsrc,
                          const void* __restrict__ gcnb, const float* __restrict__ coef,
                          const int* __restrict__ mode, void* __restrict__ out) {
    int wid  = (blockIdx.x * blockDim.x + threadIdx.x) >> 6;
    int lane = threadIdx.x & 63;
    if (wid >= NN) return;
    int half = lane >> 5, sl = lane & 31;
    int c = cnt[wid]; if (c < 0) c = 0;
    int deg = (c < CAP) ? c : CAP;
    const int* brow = bsrc + wid * CAP;

    float a0 = 0.0f, a1 = 0.0f, a2 = 0.0f, a3 = 0.0f;
    #define EDGE(idx_expr)  do { int _j = (idx_expr); \
        int _s = brow[_j & (CAP - 1)]; \
        if (_j < deg) { \
            int _cs = cnt[_s]; if (_cs < 0) _cs = 0; \
            uint2 _r = *(const uint2*)(hb + _s * 128 + sl * 4); \
            float _w = rsqrtf(1.0f + (float)_cs); \
            a0 += _w * b2f((ushort_t)(_r.x & 0xffffu)); \
            a1 += _w * b2f((ushort_t)(_r.x >> 16)); \
            a2 += _w * b2f((ushort_t)(_r.y & 0xffffu)); \
            a3 += _w * b2f((ushort_t)(_r.y >> 16)); } } while (0)

    for (int jj = 0; jj < deg; jj += 8) {   // uniform; 4 edges per half in flight
        EDGE(jj + half);
        EDGE(jj + half + 2);
        EDGE(jj + half + 4);
        EDGE(jj + half + 6);
    }
    #undef EDGE
    float d = rsqrtf(1.0f + (float)c);
    if (half == 0) {                       // self term once (weight dg[d], pre-combine)
        uint2 r = *(const uint2*)(hb + wid * 128 + sl * 4);
        a0 += d * b2f((ushort_t)(r.x & 0xffffu));
        a1 += d * b2f((ushort_t)(r.x >> 16));
        a2 += d * b2f((ushort_t)(r.y & 0xffffu));
        a3 += d * b2f((ushort_t)(r.y >> 16));
    }
    // combine halves (same feats in lane l and l^32)
    a0 += __shfl_xor(a0, 32); a1 += __shfl_xor(a1, 32);
    a2 += __shfl_xor(a2, 32); a3 += __shfl_xor(a3, 32);
    int mf = mode[0];
    int fb = sl * 4;
    float g0 = d * a0 + ldm(gcnb, fb,     mf);
    float g1 = d * a1 + ldm(gcnb, fb + 1, mf);
    float g2 = d * a2 + ldm(gcnb, fb + 2, mf);
    float g3 = d * a3 + ldm(gcnb, fb + 3, mf);
    float v = fmaxf(g0, 0.0f) * coef[512 + fb]
            + fmaxf(g1, 0.0f) * coef[512 + fb + 1]
            + fmaxf(g2, 0.0f) * coef[512 + fb + 2]
            + fmaxf(g3, 0.0f) * coef[512 + fb + 3];
    #pragma unroll
    for (int o = 32; o >= 1; o >>= 1) v += __shfl_down(v, o);   // sums both halves = 2x
    if (lane == 0) {
        float r = 0.5f * v + coef[640];
        if (mf) ((float*)out)[wid] = r;
        else    ((ushort_t*)out)[wid] = f2b(r);
    }
}

extern "C" void kernel_launch(void* const* d_in, const int* in_sizes, int n_in,
                              void* d_out, int out_size, void* d_ws, size_t ws_size,
                              hipStream_t stream) {
    if (ws_size < (size_t)WS_REQ) {   // diagnostic: finite 0.088 failure, not NaN
        fb_k<<<(out_size + 255) / 256, 256, 0, stream>>>((ushort_t*)d_out, out_size);
        return;
    }
    const void* x    = d_in[0];
    const int*  ei   = (const int*)d_in[1];
    // d_in[2] edge_weight: unused (ChebConv of zero state collapses to bias)
    const void* Wx   = d_in[3];
    const void* wc   = d_in[4];
    const void* bb   = d_in[5];
    // d_in[6] theta: unused
    const void* thb  = d_in[7];
    const void* gcnw = d_in[8];
    const void* gcnb = d_in[9];
    const void* gam  = d_in[10];
    const void* bet  = d_in[11];
    const void* mea  = d_in[12];
    const void* var  = d_in[13];
    const void* linw = d_in[14];
    const void* linb = d_in[15];

    char* ws = (char*)d_ws;
    ushort_t* hb   = (ushort_t*)(ws + OFF_HB);
    int*      bsrc = (int*)     (ws + OFF_BSRC);
    int*      cnt  = (int*)     (ws + OFF_CNT);
    ushort_t* WT   = (ushort_t*)(ws + OFF_WT);
    float*    coef = (float*)   (ws + OFF_COEF);
    int*      mode = (int*)     (ws + OFF_MODE);

    init_k<<<NP + 1, 256, 0, stream>>>((const ushort_t*)x, cnt, mode);
    prep_k<<<33, 256, 0, stream>>>(Wx, gcnw, wc, bb, thb, gam, bet, mea, var, linw, linb, mode, WT, coef);
    gafi_k<<<NGB, 256, 0, stream>>>(x, WT, coef, mode, hb, ei, cnt, bsrc);
    gat_out_k<<<(NN * 64 + 255) / 256, 256, 0, stream>>>(hb, cnt, bsrc, gcnb, coef, mode, d_out);
}

// Round 14
// 190.918 us; speedup vs baseline: 1.0692x; 1.0692x over previous
//
#include <hip/hip_runtime.h>
#include <hip/hip_bf16.h>

// Problem constants (reference: N, E, K, F_IN, H = 50000, 640000, 3, 128, 128)
#define NN 50000
#define NE 640000
#define NP 196          // ceil(NN/256) zero blocks
#define CAP 64          // bucket capacity; deg~Poisson(12.8), P(deg>=64)~5e-27
#define NGB 782         // gates blocks: ceil(NN/64); blocks 0..624 also fill (NE/1024=625)
#define CS  16          // cnt stride (ints): one counter per 64B L2 line

typedef unsigned short ushort_t;
typedef unsigned int uint_t;
typedef __attribute__((ext_vector_type(8))) short bf16x8;   // 8 bf16 = 4 VGPRs
typedef __attribute__((ext_vector_type(4))) float f32x4;

__device__ __forceinline__ float b2f(ushort_t u) {
    union { uint_t u; float f; } v; v.u = ((uint_t)u) << 16; return v.f;
}
__device__ __forceinline__ ushort_t f2b(float f) {
    union { float f; uint_t u; } v; v.f = f;
    uint_t u = v.u;
    uint_t r = u + 0x7fffu + ((u >> 16) & 1u);   // round-nearest-even
    return (ushort_t)(r >> 16);
}
// fast transcendentals: v_exp + v_rcp (err ~1e-6, vs 4.9e-4 pipeline absmax)
__device__ __forceinline__ float fsig(float x)  { return __builtin_amdgcn_rcpf(1.0f + __expf(-x)); }
__device__ __forceinline__ float ftanh(float x) { return 1.0f - 2.0f * __builtin_amdgcn_rcpf(1.0f + __expf(2.0f * x)); }
// mode-aware scalar param load: mf=1 -> f32 array, mf=0 -> bf16 array
__device__ __forceinline__ float ldm(const void* p, int i, int mf) {
    return mf ? ((const float*)p)[i] : b2f(((const ushort_t*)p)[i]);
}

// ---- workspace layout (bytes), total 28.93 MB (known-good ceiling: 31.65 MB) ----
#define OFF_HB   0            // NN*128 bf16 (12,800,000)  raw h (post-gcn_w), bf16
#define OFF_BSRC 12800000     // NN*CAP i32 (12,800,000)   fixed-capacity dst buckets
#define OFF_CNT  25600000     // NN*CS i32  (3,200,000)    in-degree, 1 counter / 64B line
#define OFF_WT   28800000     // 4*16384 bf16 (131,072)    Wi^T, Wc^T, Wo^T, gcn_w^T ([f][k])
#define OFF_COEF 28931072     // 641 f32    (2,564)
#define OFF_MODE 28933640     // i32
#define WS_REQ   28933648

__global__ void fb_k(ushort_t* __restrict__ out, int n) {   // ws too small: diagnostic zeros
    int i = blockIdx.x * blockDim.x + threadIdx.x;
    if (i < n) out[i] = 0;
}

// blocks 0..NP-1: zero cnt (strided slots only). block NP: dtype detect
// (f32-as-bf16 halves show huge exponents ~25% >= 0xC0; real bf16 never does).
__global__ void init_k(const ushort_t* __restrict__ x, int* __restrict__ cnt,
                       int* __restrict__ mode) {
    __shared__ int s[256];
    int b = blockIdx.x, t = threadIdx.x;
    if (b < NP) {
        int i = b * 256 + t;
        if (i < NN) cnt[i * CS] = 0;
    } else {
        int bad = 0;
        for (int i = t; i < 4096; i += 256) {
            int e = (x[i] >> 7) & 0xFF;
            if (e >= 0xC0) bad++;
        }
        s[t] = bad; __syncthreads();
        for (int o = 128; o >= 1; o >>= 1) { if (t < o) s[t] += s[t + o]; __syncthreads(); }
        if (t == 0) mode[0] = (s[0] > 8) ? 1 : 0;   // 1 = f32 inputs, 0 = bf16
    }
}

// blocks 0..31: transpose W_x[0],W_x[2],W_x[3],gcn_w -> bf16 [f][k] with
// coalesced 16B reads + fire-and-forget scattered stores.
// block 32: fold biases (cheb(0)=theta_b), peephole w_c[2], relu->BN->linear tail.
__global__ void prep_k(const void* __restrict__ Wx, const void* __restrict__ gcnw,
                       const void* __restrict__ wc, const void* __restrict__ bb,
                       const void* __restrict__ thb,
                       const void* __restrict__ gam, const void* __restrict__ bet,
                       const void* __restrict__ mea, const void* __restrict__ var,
                       const void* __restrict__ linw, const void* __restrict__ linb,
                       const int* __restrict__ mode,
                       ushort_t* __restrict__ WT, float* __restrict__ coef) {
    __shared__ float red[128];
    int b = blockIdx.x, t = threadIdx.x;
    int mf = mode[0];
    if (b < 32) {
        int gid = b * 256 + t;          // 0..8191, 2048 threads/matrix
        int m  = gid >> 11;
        int u  = gid & 2047;
        int k  = u >> 4;
        int f0 = (u & 15) << 3;
        const int srcoff[4] = { 0, 2 * 16384, 3 * 16384, 0 };
        const void* S = (m == 3) ? gcnw : Wx;
        int sbase = srcoff[m] + k * 128 + f0;
        ushort_t vals[8];
        if (mf == 0) {
            bf16x8 v = *(const bf16x8*)((const ushort_t*)S + sbase);
            #pragma unroll
            for (int i = 0; i < 8; i++) vals[i] = (ushort_t)v[i];
        } else {
            const float* Sf = (const float*)S + sbase;
            #pragma unroll
            for (int i = 0; i < 8; i++) vals[i] = f2b(Sf[i]);
        }
        ushort_t* D = WT + m * 16384 + k;
        #pragma unroll
        for (int i = 0; i < 8; i++) D[(f0 + i) * 128] = vals[i];
    } else {
        if (t < 128) {
            float rs = rsqrtf(ldm(var, t, mf) + 1e-5f);
            float ga = ldm(gam, t, mf);
            float lw = ldm(linw, t, mf);
            coef[t]       = ldm(thb, t, mf)           + ldm(bb, t, mf);            // bias_i
            coef[128 + t] = ldm(thb, 2 * 128 + t, mf) + ldm(bb, 2 * 128 + t, mf);  // bias_c
            coef[256 + t] = ldm(thb, 3 * 128 + t, mf) + ldm(bb, 3 * 128 + t, mf);  // bias_o
            coef[384 + t] = ldm(wc, 2 * 128 + t, mf);                              // w_c[2]
            coef[512 + t] = ga * rs * lw;                                          // s[f]
            red[t] = (ldm(bet, t, mf) - ldm(mea, t, mf) * ga * rs) * lw;
        }
        __syncthreads();
        for (int off = 64; off >= 1; off >>= 1) {
            if (t < off && t < 128) red[t] += red[t + off];
            __syncthreads();
        }
        if (t == 0) coef[640] = red[0] + ldm(linb, 0, mf);                         // C
    }
}

// ---------------------------------------------------------------------------
// Homogeneous fused kernel: EVERY block does gates GEMM; blocks 0..624 also
// bucket a 1024-edge quota (4/thread int4). Atomics (to line-strided cnt)
// issue after the A-frag barrier; returns consumed after the post-Hs barrier.
// R14: cnt stride = 64B/counter — R12/R13's dense cnt packed 16 counters per
// L2 line (205 RMWs/line serialized); spreading lifts line-level parallelism.
//   gates: one block = 4 waves = 64 nodes; wave w owns feature cols
//   [32w,32w+32) (B-frags load once, reuse over 4 row tiles). Stores RAW h.
//   MFMA f32_16x16x32_bf16 layouts (HW-verified):
//   A: a[j]=A[m=lane&15][k=(lane>>4)*8+j];  B: b[j]=B[k=(lane>>4)*8+j][n=lane&15]
//   D: reg r -> row (lane>>4)*4+r, col lane&15
// ---------------------------------------------------------------------------
__launch_bounds__(256)
__global__ void gafi_k(const void* __restrict__ x, const ushort_t* __restrict__ WT,
                       const float* __restrict__ coef, const int* __restrict__ mode,
                       ushort_t* __restrict__ hb,
                       const int* __restrict__ ei, int* __restrict__ cnt,
                       int* __restrict__ bsrc) {
    __shared__ ushort_t tile[64 * 136];   // +8 pad: row stride 272B
    int b = blockIdx.x, t = threadIdx.x;
    bool doFill = (b < 625);              // 625*256*4 = NE exactly
    int4 s4, d4;
    if (doFill) {
        int tid = b * 256 + t;
        s4 = ((const int4*)ei)[tid];
        d4 = ((const int4*)(ei + NE))[tid];
    }

    int base = b * 64;
    int mf = mode[0];
    for (int i = 0; i < 4; i++) {
        int idx = (i * 256 + t) * 8;
        int row = idx >> 7, col = idx & 127;
        int n = base + row;
        bf16x8 v;
        if (n >= NN) {
            v = (bf16x8)0;
        } else if (mf == 0) {
            v = *(const bf16x8*)((const ushort_t*)x + n * 128 + col);
        } else {
            const float* xf = (const float*)x + n * 128 + col;
            float4 lo = *(const float4*)xf;
            float4 hi = *(const float4*)(xf + 4);
            v[0] = (short)f2b(lo.x); v[1] = (short)f2b(lo.y);
            v[2] = (short)f2b(lo.z); v[3] = (short)f2b(lo.w);
            v[4] = (short)f2b(hi.x); v[5] = (short)f2b(hi.y);
            v[6] = (short)f2b(hi.z); v[7] = (short)f2b(hi.w);
        }
        *(bf16x8*)&tile[row * 136 + col] = v;
    }
    __syncthreads();

    int lane = t & 63, wave = t >> 6;
    int m = lane & 15, quad = lane >> 4;

    bf16x8 a[4][4];
    #pragma unroll
    for (int rt = 0; rt < 4; rt++)
        #pragma unroll
        for (int kt = 0; kt < 4; kt++)
            a[rt][kt] = *(const bf16x8*)&tile[(rt * 16 + m) * 136 + kt * 32 + quad * 8];
    __syncthreads();   // all x reads done before Hs overwrites tile

    // issue returning atomics NOW; stage-1 below covers their latency
    int p0, p1, p2, p3;
    if (doFill) {
        p0 = atomicAdd(&cnt[d4.x * CS], 1);
        p1 = atomicAdd(&cnt[d4.y * CS], 1);
        p2 = atomicAdd(&cnt[d4.z * CS], 1);
        p3 = atomicAdd(&cnt[d4.w * CS], 1);
    }

    const ushort_t* WTi = WT;
    const ushort_t* WTc = WT + 16384;
    const ushort_t* WTo = WT + 2 * 16384;

    #pragma unroll
    for (int ft = 0; ft < 2; ft++) {
        int f = wave * 32 + ft * 16 + m;
        bf16x8 bi[4], bc[4], bo[4];
        #pragma unroll
        for (int kt = 0; kt < 4; kt++) {
            int off = f * 128 + kt * 32 + quad * 8;
            bi[kt] = *(const bf16x8*)(WTi + off);
            bc[kt] = *(const bf16x8*)(WTc + off);
            bo[kt] = *(const bf16x8*)(WTo + off);
        }
        float bi_f = coef[f], bc_f = coef[128 + f], bo_f = coef[256 + f], w2 = coef[384 + f];
        #pragma unroll
        for (int rt = 0; rt < 4; rt++) {
            f32x4 ai = {0,0,0,0}, ac = {0,0,0,0}, ao = {0,0,0,0};
            #pragma unroll
            for (int kt = 0; kt < 4; kt++) {
                ai = __builtin_amdgcn_mfma_f32_16x16x32_bf16(a[rt][kt], bi[kt], ai, 0, 0, 0);
                ac = __builtin_amdgcn_mfma_f32_16x16x32_bf16(a[rt][kt], bc[kt], ac, 0, 0, 0);
                ao = __builtin_amdgcn_mfma_f32_16x16x32_bf16(a[rt][kt], bo[kt], ao, 0, 0, 0);
            }
            #pragma unroll
            for (int r = 0; r < 4; r++) {
                float I  = fsig(ai[r] + bi_f);
                float T  = ftanh(ac[r] + bc_f);
                float Cs = I * T;                       // F*C_prev = 0
                float O  = fsig(ao[r] + w2 * Cs + bo_f);
                float Hs = O * ftanh(Cs);
                tile[(rt * 16 + quad * 4 + r) * 136 + f] = f2b(Hs);
            }
        }
    }
    __syncthreads();   // Hs tile complete; atomics drained under stage-1

    if (doFill) {      // consume atomic returns: fire-and-forget bucket stores
        if (p0 < CAP) bsrc[d4.x * CAP + p0] = s4.x;
        if (p1 < CAP) bsrc[d4.y * CAP + p1] = s4.y;
        if (p2 < CAP) bsrc[d4.z * CAP + p2] = s4.z;
        if (p3 < CAP) bsrc[d4.w * CAP + p3] = s4.w;
    }

    const ushort_t* WTg = WT + 3 * 16384;
    bf16x8 ah[4][4];
    #pragma unroll
    for (int rt = 0; rt < 4; rt++)
        #pragma unroll
        for (int kt = 0; kt < 4; kt++)
            ah[rt][kt] = *(const bf16x8*)&tile[(rt * 16 + m) * 136 + kt * 32 + quad * 8];

    #pragma unroll
    for (int ft = 0; ft < 2; ft++) {
        int f = wave * 32 + ft * 16 + m;
        bf16x8 bg[4];
        #pragma unroll
        for (int kt = 0; kt < 4; kt++)
            bg[kt] = *(const bf16x8*)(WTg + f * 128 + kt * 32 + quad * 8);
        #pragma unroll
        for (int rt = 0; rt < 4; rt++) {
            f32x4 acc = {0,0,0,0};
            #pragma unroll
            for (int kt = 0; kt < 4; kt++)
                acc = __builtin_amdgcn_mfma_f32_16x16x32_bf16(ah[rt][kt], bg[kt], acc, 0, 0, 0);
            #pragma unroll
            for (int r = 0; r < 4; r++) {
                int n = base + rt * 16 + quad * 4 + r;
                if (n < NN) hb[n * 128 + f] = f2b(acc[r]);   // RAW h (no dg pre-scale)
            }
        }
    }
}

// ---------------------------------------------------------------------------
// Fused gather + self-loop + relu->BN->linear. One wave per destination.
// R12's EXACT measured-good shape (R13's 4-deep predicated rewrite regressed
// 14us — more VMEM ops past deg): half-wave per edge, 2-deep with speculative
// in-bounds index prefetch; per-edge dg[s] from L2-resident strided cnt.
// g[d] = dg[d]*(sum_e dg[s]*h[s] + dg[d]*h[d])
// ---------------------------------------------------------------------------
__launch_bounds__(256)
__global__ void gat_out_k(const ushort_t* __restrict__ hb, const int* __restrict__ cnt,
                          const int* __restrict__ bsrc,
                          const void* __restrict__ gcnb, const float* __restrict__ coef,
                          const int* __restrict__ mode, void* __restrict__ out) {
    int wid  = (blockIdx.x * blockDim.x + threadIdx.x) >> 6;
    int lane = threadIdx.x & 63;
    if (wid >= NN) return;
    int half = lane >> 5, sl = lane & 31;
    int c = cnt[wid * CS]; if (c < 0) c = 0;
    int deg = (c < CAP) ? c : CAP;
    const int* brow = bsrc + wid * CAP;

    float a0 = 0.0f, a1 = 0.0f, a2 = 0.0f, a3 = 0.0f;
    int s0 = brow[half];                   // in-bounds slots; value valid iff idx < deg
    int s1 = brow[half + 2];
    for (int j = half; j < deg; j += 4) {
        int sn0 = brow[(j + 4) & (CAP - 1)];   // speculative prefetch, in-bounds
        int sn1 = brow[(j + 6) & (CAP - 1)];
        {   // edge j: valid (loop condition)
            int cs = cnt[s0 * CS]; if (cs < 0) cs = 0;
            uint2 r = *(const uint2*)(hb + s0 * 128 + sl * 4);
            float w = rsqrtf(1.0f + (float)cs);
            a0 += w * b2f((ushort_t)(r.x & 0xffffu));
            a1 += w * b2f((ushort_t)(r.x >> 16));
            a2 += w * b2f((ushort_t)(r.y & 0xffffu));
            a3 += w * b2f((ushort_t)(r.y >> 16));
        }
        if (j + 2 < deg) {
            int cs = cnt[s1 * CS]; if (cs < 0) cs = 0;
            uint2 r = *(const uint2*)(hb + s1 * 128 + sl * 4);
            float w = rsqrtf(1.0f + (float)cs);
            a0 += w * b2f((ushort_t)(r.x & 0xffffu));
            a1 += w * b2f((ushort_t)(r.x >> 16));
            a2 += w * b2f((ushort_t)(r.y & 0xffffu));
            a3 += w * b2f((ushort_t)(r.y >> 16));
        }
        s0 = sn0; s1 = sn1;
    }
    float d = rsqrtf(1.0f + (float)c);
    if (half == 0) {                       // self term once (weight dg[d], pre-combine)
        uint2 r = *(const uint2*)(hb + wid * 128 + sl * 4);
        a0 += d * b2f((ushort_t)(r.x & 0xffffu));
        a1 += d * b2f((ushort_t)(r.x >> 16));
        a2 += d * b2f((ushort_t)(r.y & 0xffffu));
        a3 += d * b2f((ushort_t)(r.y >> 16));
    }
    // combine halves (same feats in lane l and l^32)
    a0 += __shfl_xor(a0, 32); a1 += __shfl_xor(a1, 32);
    a2 += __shfl_xor(a2, 32); a3 += __shfl_xor(a3, 32);
    int mf = mode[0];
    int fb = sl * 4;
    float g0 = d * a0 + ldm(gcnb, fb,     mf);
    float g1 = d * a1 + ldm(gcnb, fb + 1, mf);
    float g2 = d * a2 + ldm(gcnb, fb + 2, mf);
    float g3 = d * a3 + ldm(gcnb, fb + 3, mf);
    float v = fmaxf(g0, 0.0f) * coef[512 + fb]
            + fmaxf(g1, 0.0f) * coef[512 + fb + 1]
            + fmaxf(g2, 0.0f) * coef[512 + fb + 2]
            + fmaxf(g3, 0.0f) * coef[512 + fb + 3];
    #pragma unroll
    for (int o = 32; o >= 1; o >>= 1) v += __shfl_down(v, o);   // sums both halves = 2x
    if (lane == 0) {
        float r = 0.5f * v + coef[640];
        if (mf) ((float*)out)[wid] = r;
        else    ((ushort_t*)out)[wid] = f2b(r);
    }
}

extern "C" void kernel_launch(void* const* d_in, const int* in_sizes, int n_in,
                              void* d_out, int out_size, void* d_ws, size_t ws_size,
                              hipStream_t stream) {
    if (ws_size < (size_t)WS_REQ) {   // diagnostic: finite 0.088 failure, not NaN
        fb_k<<<(out_size + 255) / 256, 256, 0, stream>>>((ushort_t*)d_out, out_size);
        return;
    }
    const void* x    = d_in[0];
    const int*  ei   = (const int*)d_in[1];
    // d_in[2] edge_weight: unused (ChebConv of zero state collapses to bias)
    const void* Wx   = d_in[3];
    const void* wc   = d_in[4];
    const void* bb   = d_in[5];
    // d_in[6] theta: unused
    const void* thb  = d_in[7];
    const void* gcnw = d_in[8];
    const void* gcnb = d_in[9];
    const void* gam  = d_in[10];
    const void* bet  = d_in[11];
    const void* mea  = d_in[12];
    const void* var  = d_in[13];
    const void* linw = d_in[14];
    const void* linb = d_in[15];

    char* ws = (char*)d_ws;
    ushort_t* hb   = (ushort_t*)(ws + OFF_HB);
    int*      bsrc = (int*)     (ws + OFF_BSRC);
    int*      cnt  = (int*)     (ws + OFF_CNT);
    ushort_t* WT   = (ushort_t*)(ws + OFF_WT);
    float*    coef = (float*)   (ws + OFF_COEF);
    int*      mode = (int*)     (ws + OFF_MODE);

    init_k<<<NP + 1, 256, 0, stream>>>((const ushort_t*)x, cnt, mode);
    prep_k<<<33, 256, 0, stream>>>(Wx, gcnw, wc, bb, thb, gam, bet, mea, var, linw, linb, mode, WT, coef);
    gafi_k<<<NGB, 256, 0, stream>>>(x, WT, coef, mode, hb, ei, cnt, bsrc);
    gat_out_k<<<(NN * 64 + 255) / 256, 256, 0, stream>>>(hb, cnt, bsrc, gcnb, coef, mode, d_out);
}